// Round 9
// baseline (3464.986 us; speedup 1.0000x reference)
//
#include <hip/hip_runtime.h>
#include <math.h>

// ---------------------------------------------------------------------------
// V=4096, READ_F=24, INFO_F=10, REF_LEN=25, CONV_C=32, KERN=3
// READ_E=128, INFO_E=64, SEQ_E=64, EMB=256, FFN=512, BLOCKS=2
// x in bf16; epilogue math fp32; gate bf16; weights packed fragment-order.
// Segment reductions fused into producer epilogues via f32 atomics.
// ---------------------------------------------------------------------------

typedef short short8 __attribute__((ext_vector_type(8)));
typedef __bf16 bf16x8 __attribute__((ext_vector_type(8)));
typedef float f32x4 __attribute__((ext_vector_type(4)));

__device__ inline unsigned short f2bf(float f) {
    unsigned u = __builtin_bit_cast(unsigned, f);
    u += 0x7fffu + ((u >> 16) & 1u);   // RNE
    return (unsigned short)(u >> 16);
}
__device__ inline float bf2f(unsigned short u) {
    unsigned v = ((unsigned)u) << 16;
    return __builtin_bit_cast(float, v);
}

__device__ inline f32x4 mfma16(short8 a, short8 b, f32x4 c) {
    return __builtin_amdgcn_mfma_f32_16x16x32_bf16(
        __builtin_bit_cast(bf16x8, a), __builtin_bit_cast(bf16x8, b), c, 0, 0, 0);
}

// XOR-swizzled LDS element index (16B granule): elem = k ^ ((row&mask)<<3)
__device__ inline int lds_idx(int row, int k, int Kp, int mask) {
    return row * Kp + (k ^ ((row & mask) << 3));
}

// ---------------- scan: offsets + ids + inv-counts + inv-wsum --------------
__global__ __launch_bounds__(256) void scan_fill(
        const int* __restrict__ cref, const int* __restrict__ calt,
        const float* __restrict__ au,
        int* __restrict__ off_r, int* __restrict__ off_a,
        int* __restrict__ rid_r, int* __restrict__ rid_a,
        float* __restrict__ invcnt, float* __restrict__ winv, int V) {
    __shared__ int part[256];
    const int isalt = blockIdx.x;
    const int* cnt = isalt ? calt : cref;
    int* off = isalt ? off_a : off_r;
    int* rid = isalt ? rid_a : rid_r;
    int t = threadIdx.x;
    int items = (V + 255) >> 8;
    int base = t * items;
    int s = 0;
    for (int i = 0; i < items; i++) {
        int idx = base + i;
        if (idx < V) s += cnt[idx];
    }
    part[t] = s;
    __syncthreads();
    for (int d = 1; d < 256; d <<= 1) {
        int v = (t >= d) ? part[t - d] : 0;
        __syncthreads();
        part[t] += v;
        __syncthreads();
    }
    int run = (t == 0) ? 0 : part[t - 1];
    for (int i = 0; i < items; i++) {
        int idx = base + i;
        if (idx < V) {
            off[idx] = run;
            run += cnt[idx];
        }
    }
    if (t == 255) off[V] = part[255];
    __syncthreads();
    for (int v = t; v < V; v += 256) {
        int s0 = off[v], e0 = off[v + 1];
        for (int r = s0; r < e0; r++) rid[r] = v;
        if (isalt) {
            invcnt[v] = 1.f / (float)(e0 - s0);      // alt-mean rows [0,V)
            float ws = 0.f;
            for (int r = s0; r < e0; r++) ws += 1.2f - 0.4f * au[r];
            winv[v] = 1.f / ws;
        } else {
            invcnt[V + v] = 1.f / (float)(e0 - s0);  // ref-mean rows [V,2V)
        }
    }
}

// ---------------- weight repacks + accumulator zeroing (one kernel) --------
__device__ inline void pack_one(const float* __restrict__ src,
                                unsigned short* __restrict__ dst, int i,
                                int Ksrc, int K, int N, int ctN) {
    int e = i & 7;
    int lane = (i >> 3) & 63;
    int li = lane & 15, lg = lane >> 4;
    int r = i >> 9;
    int ct = r % ctN;
    int r2 = r / ctN;
    int sN = K >> 5;
    int s = r2 % sN;
    int strip = r2 / sN;
    int n = strip * (ctN << 4) + (ct << 4) + li;
    int k = (s << 5) + (lg << 3) + e;
    dst[i] = (k < Ksrc) ? f2bf(src[(size_t)k * N + n]) : (unsigned short)0;
}

__global__ __launch_bounds__(256) void pack_all(
        const float* __restrict__ w1, const float* __restrict__ wg,
        const float* __restrict__ w2, const float* __restrict__ rw1,
        const float* __restrict__ rw2, const float* __restrict__ ag1,
        const float* __restrict__ ag2,
        unsigned short* W1p0, unsigned short* W1p1,
        unsigned short* Wgp0, unsigned short* Wgp1,
        unsigned short* W2p0, unsigned short* W2p1,
        unsigned short* RW1p, unsigned short* RW2p,
        unsigned short* AG1p, unsigned short* AG2p,
        float* __restrict__ zbuf, int zcount) {
    int idx = blockIdx.x * 256 + threadIdx.x;
    if (idx < 131072)       pack_one(w1,          W1p0, idx,          256, 256, 512, 4);
    else if (idx < 262144)  pack_one(w1 + 131072, W1p1, idx - 131072, 256, 256, 512, 4);
    else if (idx < 393216)  pack_one(wg,          Wgp0, idx - 262144, 256, 256, 512, 4);
    else if (idx < 524288)  pack_one(wg + 131072, Wgp1, idx - 393216, 256, 256, 512, 4);
    else if (idx < 655360)  pack_one(w2,          W2p0, idx - 524288, 512, 512, 256, 2);
    else if (idx < 786432)  pack_one(w2 + 131072, W2p1, idx - 655360, 512, 512, 256, 2);
    else if (idx < 790528)  pack_one(rw1,         RW1p, idx - 786432, 24, 32, 128, 1);
    else if (idx < 806912)  pack_one(rw2,         RW2p, idx - 790528, 128, 128, 128, 1);
    else if (idx < 872448)  pack_one(ag1,         AG1p, idx - 806912, 256, 256, 256, 4);
    else if (idx < 905216)  pack_one(ag2,         AG2p, idx - 872448, 256, 256, 128, 4);
    else {
        int zi = idx - 905216;
        if (zi < zcount) zbuf[zi] = 0.f;
    }
}

// ---------------- generic MFMA GEMM: C = epi(A[M,K] @ W + bias) ------------
// W packed ctN=4 (64-col strip per blockIdx.y).
// EPI: 0 fp32, 1 relu->bf16, 2 sigmoid->bf16
// SRCF: 0 A is bf16 [M][K]; 1 A is f32 [M][K] scaled by scale[row] (null=1)
template <int EPI, int SRCF>
__global__ __launch_bounds__(256, 4) void gemm_bf16(
        const void* __restrict__ Araw, const unsigned short* __restrict__ Bp,
        const float* __restrict__ bias, void* __restrict__ C0,
        const float* __restrict__ scale, int M, int K, int mask, int ldc) {
    extern __shared__ unsigned short As[];
    const int m0 = blockIdx.x * 64, n0 = blockIdx.y * 64;
    const int tid = threadIdx.x;
    const int kc = K >> 3;
    for (int i = tid; i < (kc << 6); i += 256) {
        int r = i / kc, k8 = (i - r * kc) << 3;
        short8 v = {0, 0, 0, 0, 0, 0, 0, 0};
        if (m0 + r < M) {
            if (SRCF) {
                const float* ap = (const float*)Araw + (size_t)(m0 + r) * K + k8;
                float sc = scale ? scale[m0 + r] : 1.f;
#pragma unroll
                for (int e = 0; e < 8; e++) v[e] = (short)f2bf(ap[e] * sc);
            } else {
                v = *(const short8*)((const unsigned short*)Araw + (size_t)(m0 + r) * K + k8);
            }
        }
        *(short8*)&As[lds_idx(r, k8, K, mask)] = v;
    }
    __syncthreads();
    const int wid = tid >> 6, lane = tid & 63;
    const int lr = lane & 15, lg = lane >> 4;
    f32x4 acc[4];
#pragma unroll
    for (int ct = 0; ct < 4; ++ct) acc[ct] = f32x4{0.f, 0.f, 0.f, 0.f};
    const unsigned short* Bb = Bp + (size_t)blockIdx.y * ((size_t)K << 6) + (lane << 3);
    const int nk = K >> 5;
    for (int s = 0; s < nk; ++s) {
        int k0 = (s << 5) + (lg << 3);
        short8 af = *(const short8*)&As[lds_idx((wid << 4) + lr, k0, K, mask)];
#pragma unroll
        for (int ct = 0; ct < 4; ++ct) {
            short8 bf = *(const short8*)(Bb + (s << 11) + (ct << 9));
            acc[ct] = mfma16(af, bf, acc[ct]);
        }
    }
#pragma unroll
    for (int ct = 0; ct < 4; ++ct) {
        int c = n0 + (ct << 4) + lr;
        float bb = bias[c];
#pragma unroll
        for (int q = 0; q < 4; ++q) {
            int rg = m0 + (wid << 4) + (lg << 2) + q;
            if (rg >= M) continue;
            float v = acc[ct][q] + bb;
            if (EPI == 0) {
                ((float*)C0)[(size_t)rg * ldc + c] = v;
            } else if (EPI == 1) {
                ((unsigned short*)C0)[(size_t)rg * ldc + c] = f2bf(fmaxf(v, 0.f));
            } else {
                ((unsigned short*)C0)[(size_t)rg * ldc + c] = f2bf(1.f / (1.f + __expf(-v)));
            }
        }
    }
}

// ---------------- fused read MLP + isv gather + layer0 mean atomics --------
__global__ __launch_bounds__(512) void read_mlp_fused(
        const float* __restrict__ reads,
        const unsigned short* __restrict__ RW1p, const unsigned short* __restrict__ RW2p,
        const float* __restrict__ rb1, const float* __restrict__ rb2,
        const uint4* __restrict__ isv4,
        const int* __restrict__ rid_r, const int* __restrict__ rid_a,
        unsigned short* __restrict__ xref, unsigned short* __restrict__ xalt,
        float* __restrict__ m2f0, int R, int TR, int V) {
    __shared__ unsigned short Xs[64 * 32];
    __shared__ unsigned short Hs[64 * 128];
    __shared__ int rid_s[64];
    const int m0 = blockIdx.x * 64;
    const int tid = threadIdx.x;
    if (tid < 64) {
        int g = m0 + tid;
        rid_s[tid] = (g < R) ? (g < TR ? rid_r[g] : rid_a[g - TR]) : 0;
    }
    if (tid < 256) {
        int r = tid >> 2, c8 = (tid & 3) << 3;
        short8 v = {0, 0, 0, 0, 0, 0, 0, 0};
        int g = m0 + r;
        if (g < R && c8 < 24) {
            const float* sp = reads + (size_t)g * 24 + c8;
#pragma unroll
            for (int e = 0; e < 8; e++) v[e] = (short)f2bf(sp[e]);
        }
        *(short8*)&Xs[lds_idx(r, c8, 32, 3)] = v;
    }
    __syncthreads();
    const int wid = tid >> 6, lane = tid & 63;
    const int li = lane & 15, lg = lane >> 4;
    f32x4 a1[4];
#pragma unroll
    for (int rt = 0; rt < 4; ++rt) a1[rt] = f32x4{0.f, 0.f, 0.f, 0.f};
    short8 bw1 = *(const short8*)(RW1p + ((size_t)wid << 9) + (lane << 3));
#pragma unroll
    for (int rt = 0; rt < 4; ++rt) {
        short8 af = *(const short8*)&Xs[lds_idx(rt * 16 + li, lg << 3, 32, 3)];
        a1[rt] = mfma16(af, bw1, a1[rt]);
    }
    float b1v = rb1[(wid << 4) + li];
#pragma unroll
    for (int rt = 0; rt < 4; ++rt)
#pragma unroll
        for (int q = 0; q < 4; ++q) {
            int row = rt * 16 + (lg << 2) + q;
            Hs[lds_idx(row, (wid << 4) + li, 128, 15)] = f2bf(fmaxf(a1[rt][q] + b1v, 0.f));
        }
    __syncthreads();
    f32x4 a2[4];
#pragma unroll
    for (int rt = 0; rt < 4; ++rt) a2[rt] = f32x4{0.f, 0.f, 0.f, 0.f};
    const unsigned short* B2 = RW2p + ((size_t)wid << 11) + (lane << 3);
#pragma unroll
    for (int s = 0; s < 4; ++s) {
        short8 bw = *(const short8*)(B2 + (s << 9));
        int k0 = (s << 5) + (lg << 3);
#pragma unroll
        for (int rt = 0; rt < 4; ++rt) {
            short8 ah = *(const short8*)&Hs[lds_idx(rt * 16 + li, k0, 128, 15)];
            a2[rt] = mfma16(ah, bw, a2[rt]);
        }
    }
    float b2v = rb2[(wid << 4) + li];
    unsigned short ov[4][4];
#pragma unroll
    for (int rt = 0; rt < 4; ++rt)
#pragma unroll
        for (int q = 0; q < 4; ++q) ov[rt][q] = f2bf(a2[rt][q] + b2v);
    __syncthreads();
#pragma unroll
    for (int rt = 0; rt < 4; ++rt)
#pragma unroll
        for (int q = 0; q < 4; ++q) {
            int row = rt * 16 + (lg << 2) + q;
            Hs[row * 128 + (wid << 4) + li] = ov[rt][q];   // OutS linear
        }
    __syncthreads();
    // ---- store x + isv gather + atomic layer0 segment sums ----
#pragma unroll
    for (int u = 0; u < 4; ++u) {
        int i = tid + (u << 9);
        int r = i >> 5, j = i & 31;
        int g = m0 + r;
        if (g >= R) continue;
        unsigned short* dst = (g < TR) ? (xref + (size_t)g * 256)
                                       : (xalt + (size_t)(g - TR) * 256);
        short8 val;
        if (j < 16)
            val = *(const short8*)&Hs[r * 128 + (j << 3)];
        else
            val = __builtin_bit_cast(short8, isv4[(size_t)rid_s[r] * 16 + (j - 16)]);
        *(short8*)(dst + (j << 3)) = val;
        float* tgt = m2f0 + ((g < TR) ? (size_t)(V + rid_s[r]) : (size_t)rid_s[r]) * 256 + (j << 3);
#pragma unroll
        for (int e = 0; e < 8; e++) atomicAdd(&tgt[e], bf2f((unsigned short)val[e]));
    }
}

// ---------------- per-variant info MLP + conv + seq linear -> isv bf16 -----
__global__ __launch_bounds__(128) void variant_embed(
        const float* __restrict__ info2d, const float* __restrict__ oh,
        const float* __restrict__ iw1, const float* __restrict__ ib1,
        const float* __restrict__ iw2, const float* __restrict__ ib2,
        const float* __restrict__ cw, const float* __restrict__ cb,
        const float* __restrict__ sw, const float* __restrict__ sb,
        unsigned short* __restrict__ isv, int V) {
    __shared__ float iw1s[10 * 64], iw2s[64 * 64], ib1s[64], ib2s[64];
    __shared__ float cws[32 * 4 * 3], cbs[32];
    __shared__ float ohs[100], cv[736], his[64], infs[10];
    int v = blockIdx.x;
    int t = threadIdx.x;
    for (int i = t; i < 640; i += 128) iw1s[i] = iw1[i];
    for (int i = t; i < 4096; i += 128) iw2s[i] = iw2[i];
    for (int i = t; i < 384; i += 128) cws[i] = cw[i];
    if (t < 64) { ib1s[t] = ib1[t]; ib2s[t] = ib2[t]; }
    if (t < 32) cbs[t] = cb[t];
    for (int i = t; i < 100; i += 128) ohs[i] = oh[(size_t)v * 100 + i];
    if (t < 10) infs[t] = info2d[(size_t)v * 10 + t];
    __syncthreads();
    for (int j = t; j < 736; j += 128) {
        int c = j / 23, p = j - c * 23;
        float a = cbs[c];
#pragma unroll
        for (int i = 0; i < 4; i++)
#pragma unroll
            for (int k = 0; k < 3; k++)
                a += cws[(c * 4 + i) * 3 + k] * ohs[i * 25 + p + k];
        cv[j] = fmaxf(a, 0.f);
    }
    if (t < 64) {
        float h = ib1s[t];
#pragma unroll
        for (int k = 0; k < 10; k++) h += infs[k] * iw1s[k * 64 + t];
        his[t] = fmaxf(h, 0.f);
    }
    __syncthreads();
    if (t < 64) {
        float o = ib2s[t];
        for (int k = 0; k < 64; k++) o += his[k] * iw2s[k * 64 + t];
        isv[(size_t)v * 128 + t] = f2bf(o);
    } else {
        int tt = t - 64;
        float s = sb[tt];
        for (int j = 0; j < 736; j++) s += cv[j] * sw[j * 64 + tt];
        isv[(size_t)v * 128 + 64 + tt] = f2bf(s);
    }
}

// ---------------- fused gated residual block (64-row tile, 8 waves) --------
// layer 0: epilogue accumulates next-layer segment sums into macc (m2f1).
// layer 1: epilogue accumulates weighted alt sums into macc (avb_f).
__global__ __launch_bounds__(512, 4) void fused_block(
        unsigned short* __restrict__ xref, unsigned short* __restrict__ xalt,
        const unsigned short* __restrict__ W1p, const unsigned short* __restrict__ W2p,
        const float* __restrict__ b1, const float* __restrict__ b2,
        const unsigned short* __restrict__ gate_r, const unsigned short* __restrict__ gate_a,
        const int* __restrict__ rid_r, const int* __restrict__ rid_a,
        float* __restrict__ macc, const float* __restrict__ au,
        const float* __restrict__ winv, int layer,
        int TR, int TA, int ntr, int V) {
    __shared__ unsigned short U[64 * 512];        // 64 KB union
    __shared__ int rid_s[64];
    float* OutF = (float*)U;
    // bijective XCD swizzle (m204)
    const int nwg = gridDim.x;
    const int bid0 = blockIdx.x;
    const int q8 = nwg >> 3, r8 = nwg & 7;
    const int xcd = bid0 & 7;
    const int bid = (xcd < r8 ? xcd * (q8 + 1) : r8 * (q8 + 1) + (xcd - r8) * q8)
                    + (bid0 >> 3);
    const bool isref = bid < ntr;
    const int m0 = (isref ? bid : bid - ntr) * 64;
    const int M = isref ? TR : TA;
    unsigned short* x = isref ? xref : xalt;
    const unsigned short* gate = isref ? gate_r : gate_a;
    const int* rid = isref ? rid_r : rid_a;
    const int tid = threadIdx.x;
    if (tid < 64) rid_s[tid] = (m0 + tid < M) ? rid[m0 + tid] : 0;
    // ---- stage X (pre-swizzled source, linear LDS dest) ----
#pragma unroll
    for (int u = 0; u < 4; ++u) {
        int i = tid + (u << 9);
        int r = i >> 5, j = i & 31;
        short8 v = {0, 0, 0, 0, 0, 0, 0, 0};
        if (m0 + r < M)
            v = *(const short8*)(x + (size_t)(m0 + r) * 256 + ((j ^ (r & 15)) << 3));
        *(short8*)&U[r * 256 + (j << 3)] = v;
    }
    __syncthreads();
    const int wid = tid >> 6, lane = tid & 63;
    const int li = lane & 15, lg = lane >> 4;
    // ---- GEMM1 (swapped): packed W1, 1KB contiguous fragment loads ----
    const int ns = wid << 6;
    f32x4 acc1[4][4];
#pragma unroll
    for (int i = 0; i < 4; ++i)
#pragma unroll
        for (int j = 0; j < 4; ++j) acc1[i][j] = f32x4{0.f, 0.f, 0.f, 0.f};
    const unsigned short* W1b = W1p + ((size_t)wid << 14) + (lane << 3);
#pragma unroll
    for (int s = 0; s < 8; ++s) {
        short8 awc[4];
#pragma unroll
        for (int ct = 0; ct < 4; ++ct)
            awc[ct] = *(const short8*)(W1b + (s << 11) + (ct << 9));
        int k0 = (s << 5) + (lg << 3);
        __builtin_amdgcn_s_setprio(1);
#pragma unroll
        for (int rt = 0; rt < 4; ++rt) {
            short8 bx = *(const short8*)&U[lds_idx(rt * 16 + li, k0, 256, 15)];
#pragma unroll
            for (int ct = 0; ct < 4; ++ct)
                acc1[rt][ct] = mfma16(awc[ct], bx, acc1[rt][ct]);
        }
        __builtin_amdgcn_s_setprio(0);
    }
    __syncthreads();                              // Xs dead; U becomes Hs
    // ---- epilogue 1: relu * gate(bf16) -> Hs ----
#pragma unroll
    for (int rt = 0; rt < 4; ++rt) {
        int m = rt * 16 + li;
        const unsigned short* grow = gate + (size_t)rid_s[m] * 512 + ns + (lg << 2);
        const float* b1p = b1 + ns + (lg << 2);
#pragma unroll
        for (int ct = 0; ct < 4; ++ct) {
            uint2 gw = *(const uint2*)(grow + (ct << 4));
            float4 bv = *(const float4*)(b1p + (ct << 4));
            float g0 = bf2f((unsigned short)(gw.x & 0xffff));
            float g1 = bf2f((unsigned short)(gw.x >> 16));
            float g2 = bf2f((unsigned short)(gw.y & 0xffff));
            float g3 = bf2f((unsigned short)(gw.y >> 16));
            unsigned h0 = f2bf(fmaxf(acc1[rt][ct][0] + bv.x, 0.f) * g0);
            unsigned h1 = f2bf(fmaxf(acc1[rt][ct][1] + bv.y, 0.f) * g1);
            unsigned h2 = f2bf(fmaxf(acc1[rt][ct][2] + bv.z, 0.f) * g2);
            unsigned h3 = f2bf(fmaxf(acc1[rt][ct][3] + bv.w, 0.f) * g3);
            uint2 pk;
            pk.x = h0 | (h1 << 16);
            pk.y = h2 | (h3 << 16);
            int n = ns + (ct << 4) + (lg << 2);
            *(uint2*)&U[lds_idx(m, n, 512, 15)] = pk;
        }
    }
    __syncthreads();
    // ---- GEMM2: packed W2, reg-dbuf ----
    f32x4 acc2[4][2];
#pragma unroll
    for (int i = 0; i < 4; ++i)
#pragma unroll
        for (int j = 0; j < 2; ++j) acc2[i][j] = f32x4{0.f, 0.f, 0.f, 0.f};
    const unsigned short* W2b = W2p + ((size_t)wid << 14) + (lane << 3);
    short8 bwc[2], bwn[2];
#pragma unroll
    for (int ct = 0; ct < 2; ++ct) bwc[ct] = *(const short8*)(W2b + (ct << 9));
#pragma unroll
    for (int s = 0; s < 16; ++s) {
        if (s < 15) {
#pragma unroll
            for (int ct = 0; ct < 2; ++ct)
                bwn[ct] = *(const short8*)(W2b + ((s + 1) << 10) + (ct << 9));
        }
        int k0 = (s << 5) + (lg << 3);
        __builtin_amdgcn_s_setprio(1);
#pragma unroll
        for (int rt = 0; rt < 4; ++rt) {
            short8 ah = *(const short8*)&U[lds_idx(rt * 16 + li, k0, 512, 15)];
#pragma unroll
            for (int ct = 0; ct < 2; ++ct)
                acc2[rt][ct] = mfma16(ah, bwc[ct], acc2[rt][ct]);
        }
        __builtin_amdgcn_s_setprio(0);
#pragma unroll
        for (int ct = 0; ct < 2; ++ct) bwc[ct] = bwn[ct];
    }
    __syncthreads();                              // Hs dead; U becomes OutF
    // ---- epilogue 2: OutF[m][c] = acc2 + b2 (f32, swizzled) ----
    const int cs = wid << 5;
#pragma unroll
    for (int ct = 0; ct < 2; ++ct) {
        int c = cs + (ct << 4) + li;
        float bb = b2[c];
#pragma unroll
        for (int rt = 0; rt < 4; ++rt)
#pragma unroll
            for (int q = 0; q < 4; ++q) {
                int m = rt * 16 + (lg << 2) + q;
                OutF[m * 256 + (c ^ (((m >> 2) & 3) << 3))] = acc2[rt][ct][q] + bb;
            }
    }
    __syncthreads();
    // ---- coalesced store + residual add + fused reduction atomics ----
#pragma unroll
    for (int u = 0; u < 4; ++u) {
        int i = tid + (u << 9);
        int r = i >> 5, j = i & 31;
        if (m0 + r >= M) continue;
        unsigned short* xp = x + (size_t)(m0 + r) * 256 + (j << 3);
        short8 xv = *(const short8*)xp;
        int c0 = (j << 3) ^ ((((r >> 2) & 3)) << 3);
        float4 f0 = *(const float4*)&OutF[r * 256 + c0];
        float4 f1 = *(const float4*)&OutF[r * 256 + c0 + 4];
        float nf[8] = {bf2f((unsigned short)xv[0]) + f0.x, bf2f((unsigned short)xv[1]) + f0.y,
                       bf2f((unsigned short)xv[2]) + f0.z, bf2f((unsigned short)xv[3]) + f0.w,
                       bf2f((unsigned short)xv[4]) + f1.x, bf2f((unsigned short)xv[5]) + f1.y,
                       bf2f((unsigned short)xv[6]) + f1.z, bf2f((unsigned short)xv[7]) + f1.w};
        short8 o;
#pragma unroll
        for (int e = 0; e < 8; e++) o[e] = (short)f2bf(nf[e]);
        *(short8*)xp = o;
        if (layer == 0) {
            float* tgt = macc + (isref ? (size_t)(V + rid_s[r]) : (size_t)rid_s[r]) * 256 + (j << 3);
#pragma unroll
            for (int e = 0; e < 8; e++) atomicAdd(&tgt[e], bf2f((unsigned short)o[e]));
        } else if (!isref) {
            int g = m0 + r;
            float w = (1.2f - 0.4f * au[g]) * winv[rid_s[r]];
            float* tgt = macc + (size_t)rid_s[r] * 256 + (j << 3);
#pragma unroll
            for (int e = 0; e < 8; e++) atomicAdd(&tgt[e], bf2f((unsigned short)o[e]) * w);
        }
    }
}

// ---------------------------------------------------------------------------
extern "C" void kernel_launch(void* const* d_in, const int* in_sizes, int n_in,
                              void* d_out, int out_size, void* d_ws, size_t ws_size,
                              hipStream_t stream) {
    const float* reads = (const float*)d_in[0];
    const float* info2d = (const float*)d_in[1];
    const float* oh = (const float*)d_in[2];
    const float* au = (const float*)d_in[3];
    const int* ref_counts = (const int*)d_in[4];
    const int* alt_counts = (const int*)d_in[5];
    const float* rw1 = (const float*)d_in[6];
    const float* rb1 = (const float*)d_in[7];
    const float* rw2 = (const float*)d_in[8];
    const float* rb2 = (const float*)d_in[9];
    const float* iw1 = (const float*)d_in[10];
    const float* ib1 = (const float*)d_in[11];
    const float* iw2 = (const float*)d_in[12];
    const float* ib2 = (const float*)d_in[13];
    const float* cw = (const float*)d_in[14];
    const float* cb = (const float*)d_in[15];
    const float* sw = (const float*)d_in[16];
    const float* sb = (const float*)d_in[17];
    const float* blk_w1 = (const float*)d_in[18];
    const float* blk_b1 = (const float*)d_in[19];
    const float* blk_wg = (const float*)d_in[20];
    const float* blk_bg = (const float*)d_in[21];
    const float* blk_w2 = (const float*)d_in[22];
    const float* blk_b2 = (const float*)d_in[23];
    const float* agg_w1 = (const float*)d_in[24];
    const float* agg_b1 = (const float*)d_in[25];
    const float* agg_w2 = (const float*)d_in[26];
    const float* agg_b2 = (const float*)d_in[27];

    const int R = in_sizes[0] / 24;
    const int TA = in_sizes[3];
    const int TR = R - TA;
    const int V = in_sizes[4];

    size_t p = 0;
    auto carve = [&](size_t bytes) -> void* {
        void* q = (char*)d_ws + p;
        p = (p + bytes + 255) & ~(size_t)255;
        return q;
    };
    int* off_r = (int*)carve((V + 1) * sizeof(int));
    int* off_a = (int*)carve((V + 1) * sizeof(int));
    int* rid_r = (int*)carve((size_t)TR * sizeof(int));
    int* rid_a = (int*)carve((size_t)TA * sizeof(int));
    unsigned short* isv = (unsigned short*)carve((size_t)V * 128 * 2);
    unsigned short* xref = (unsigned short*)carve((size_t)TR * 256 * 2);
    unsigned short* xalt = (unsigned short*)carve((size_t)TA * 256 * 2);
    unsigned short* W1p0 = (unsigned short*)carve((size_t)512 * 256 * 2);
    unsigned short* W1p1 = (unsigned short*)carve((size_t)512 * 256 * 2);
    unsigned short* Wgp0 = (unsigned short*)carve((size_t)512 * 256 * 2);
    unsigned short* Wgp1 = (unsigned short*)carve((size_t)512 * 256 * 2);
    unsigned short* W2p0 = (unsigned short*)carve((size_t)256 * 512 * 2);
    unsigned short* W2p1 = (unsigned short*)carve((size_t)256 * 512 * 2);
    unsigned short* RW1p = (unsigned short*)carve((size_t)128 * 32 * 2);
    unsigned short* RW2p = (unsigned short*)carve((size_t)128 * 128 * 2);
    unsigned short* AG1p = (unsigned short*)carve((size_t)256 * 256 * 2);
    unsigned short* AG2p = (unsigned short*)carve((size_t)128 * 256 * 2);
    // f32 accumulators (zeroed each call by pack_all): m2f0 | m2f1 | avb_f
    float* zbase = (float*)carve((size_t)5 * V * 256 * sizeof(float));
    float* m2f0 = zbase;
    float* m2f1 = zbase + (size_t)2 * V * 256;
    float* avb_f = zbase + (size_t)4 * V * 256;
    const int zcount = 5 * V * 256;
    float* invcnt = (float*)carve((size_t)2 * V * sizeof(float));
    float* winv = (float*)carve((size_t)V * sizeof(float));
    unsigned short* gate2 = (unsigned short*)carve((size_t)2 * V * 512 * 2);
    unsigned short* aggh_bf = (unsigned short*)carve((size_t)V * 256 * 2);
    (void)ws_size; (void)n_in; (void)out_size;

    // ---- setup: offsets/ids/inv-counts, packing + accumulator zeroing ----
    scan_fill<<<2, 256, 0, stream>>>(ref_counts, alt_counts, au, off_r, off_a,
                                     rid_r, rid_a, invcnt, winv, V);
    {
        int tot = 905216 + zcount;
        pack_all<<<(tot + 255) / 256, 256, 0, stream>>>(
            blk_w1, blk_wg, blk_w2, rw1, rw2, agg_w1, agg_w2,
            W1p0, W1p1, Wgp0, Wgp1, W2p0, W2p1, RW1p, RW2p, AG1p, AG2p,
            zbase, zcount);
    }
    variant_embed<<<V, 128, 0, stream>>>(info2d, oh, iw1, ib1, iw2, ib2, cw, cb, sw, sb, isv, V);

    // ---- fused read MLP + isv gather + layer0 mean sums ----
    read_mlp_fused<<<(R + 63) / 64, 512, 0, stream>>>(
        reads, RW1p, RW2p, rb1, rb2, (const uint4*)isv, rid_r, rid_a,
        xref, xalt, m2f0, R, TR, V);

    // ---- 2 gated residual blocks ----
    const int ntr = (TR + 63) / 64, nta = (TA + 63) / 64;
    for (int it = 0; it < 2; ++it) {
        const unsigned short* W1p = it ? W1p1 : W1p0;
        const unsigned short* Wgp = it ? Wgp1 : Wgp0;
        const unsigned short* W2p = it ? W2p1 : W2p0;
        const float* B1 = blk_b1 + (size_t)it * 512;
        const float* Bg = blk_bg + (size_t)it * 512;
        const float* B2 = blk_b2 + (size_t)it * 256;
        float* m2f = it ? m2f1 : m2f0;

        dim3 gg(2 * V / 64, 8);
        gemm_bf16<2, 1><<<gg, 256, 64 * 256 * 2, stream>>>(
            m2f, Wgp, Bg, gate2, invcnt, 2 * V, 256, 15, 512);
        fused_block<<<ntr + nta, 512, 0, stream>>>(
            xref, xalt, W1p, W2p, B1, B2, gate2, gate2 + (size_t)V * 512,
            rid_r, rid_a, it ? avb_f : m2f1, au, winv, it, TR, TA, ntr, V);
    }

    // ---- agg MLP (reads f32 weighted sums directly) ----
    {
        dim3 ga(V / 64, 4);
        gemm_bf16<1, 1><<<ga, 256, 64 * 256 * 2, stream>>>(
            avb_f, AG1p, agg_b1, aggh_bf, nullptr, V, 256, 15, 256);
        dim3 go(V / 64, 2);
        gemm_bf16<0, 0><<<go, 256, 64 * 256 * 2, stream>>>(
            aggh_bf, AG2p, agg_b2, d_out, nullptr, V, 256, 15, 128);
    }
}

// Round 10
// 450.059 us; speedup vs baseline: 7.6990x; 7.6990x over previous
//
#include <hip/hip_runtime.h>
#include <math.h>

// ---------------------------------------------------------------------------
// V=4096, READ_F=24, INFO_F=10, REF_LEN=25, CONV_C=32, KERN=3
// READ_E=128, INFO_E=64, SEQ_E=64, EMB=256, FFN=512, BLOCKS=2
// x in bf16 everywhere; epilogue math fp32; gate bf16.
// Weights repacked to MFMA-fragment order (1KB contiguous per wave-fragment).
// fused_block GEMM2 operand-swapped -> direct coalesced-ish residual RMW.
// ---------------------------------------------------------------------------

typedef short short8 __attribute__((ext_vector_type(8)));
typedef __bf16 bf16x8 __attribute__((ext_vector_type(8)));
typedef float f32x4 __attribute__((ext_vector_type(4)));

__device__ inline unsigned short f2bf(float f) {
    unsigned u = __builtin_bit_cast(unsigned, f);
    u += 0x7fffu + ((u >> 16) & 1u);   // RNE
    return (unsigned short)(u >> 16);
}
__device__ inline float bf2f(unsigned short u) {
    unsigned v = ((unsigned)u) << 16;
    return __builtin_bit_cast(float, v);
}

__device__ inline f32x4 mfma16(short8 a, short8 b, f32x4 c) {
    return __builtin_amdgcn_mfma_f32_16x16x32_bf16(
        __builtin_bit_cast(bf16x8, a), __builtin_bit_cast(bf16x8, b), c, 0, 0, 0);
}

// XOR-swizzled LDS element index (16B granule): elem = k ^ ((row&mask)<<3)
__device__ inline int lds_idx(int row, int k, int Kp, int mask) {
    return row * Kp + (k ^ ((row & mask) << 3));
}

// ---------------- scan of counts -> offsets + per-read ids (merged) --------
__global__ __launch_bounds__(256) void scan_fill(
        const int* __restrict__ cref, const int* __restrict__ calt,
        int* __restrict__ off_r, int* __restrict__ off_a,
        int* __restrict__ rid_r, int* __restrict__ rid_a, int V) {
    __shared__ int part[256];
    const int* cnt = blockIdx.x ? calt : cref;
    int* off = blockIdx.x ? off_a : off_r;
    int* rid = blockIdx.x ? rid_a : rid_r;
    int t = threadIdx.x;
    int items = (V + 255) >> 8;
    int base = t * items;
    int s = 0;
    for (int i = 0; i < items; i++) {
        int idx = base + i;
        if (idx < V) s += cnt[idx];
    }
    part[t] = s;
    __syncthreads();
    for (int d = 1; d < 256; d <<= 1) {
        int v = (t >= d) ? part[t - d] : 0;
        __syncthreads();
        part[t] += v;
        __syncthreads();
    }
    int run = (t == 0) ? 0 : part[t - 1];
    for (int i = 0; i < items; i++) {
        int idx = base + i;
        if (idx < V) {
            off[idx] = run;
            run += cnt[idx];
        }
    }
    if (t == 255) off[V] = part[255];
    __syncthreads();
    for (int v = t; v < V; v += 256) {
        int s0 = off[v], e0 = off[v + 1];
        for (int r = s0; r < e0; r++) rid[r] = v;
    }
}

// ---------------- all weight repacks in ONE kernel -------------------------
__device__ inline void pack_one(const float* __restrict__ src,
                                unsigned short* __restrict__ dst, int i,
                                int Ksrc, int K, int N, int ctN) {
    int e = i & 7;
    int lane = (i >> 3) & 63;
    int li = lane & 15, lg = lane >> 4;
    int r = i >> 9;
    int ct = r % ctN;
    int r2 = r / ctN;
    int sN = K >> 5;
    int s = r2 % sN;
    int strip = r2 / sN;
    int n = strip * (ctN << 4) + (ct << 4) + li;
    int k = (s << 5) + (lg << 3) + e;
    dst[i] = (k < Ksrc) ? f2bf(src[(size_t)k * N + n]) : (unsigned short)0;
}

__global__ __launch_bounds__(256) void pack_all(
        const float* __restrict__ w1, const float* __restrict__ wg,
        const float* __restrict__ w2, const float* __restrict__ rw1,
        const float* __restrict__ rw2, const float* __restrict__ ag1,
        const float* __restrict__ ag2,
        unsigned short* W1p0, unsigned short* W1p1,
        unsigned short* Wgp0, unsigned short* Wgp1,
        unsigned short* W2p0, unsigned short* W2p1,
        unsigned short* RW1p, unsigned short* RW2p,
        unsigned short* AG1p, unsigned short* AG2p) {
    int idx = blockIdx.x * 256 + threadIdx.x;
    if (idx < 131072)       pack_one(w1,          W1p0, idx,          256, 256, 512, 4);
    else if (idx < 262144)  pack_one(w1 + 131072, W1p1, idx - 131072, 256, 256, 512, 4);
    else if (idx < 393216)  pack_one(wg,          Wgp0, idx - 262144, 256, 256, 512, 4);
    else if (idx < 524288)  pack_one(wg + 131072, Wgp1, idx - 393216, 256, 256, 512, 4);
    else if (idx < 655360)  pack_one(w2,          W2p0, idx - 524288, 512, 512, 256, 2);
    else if (idx < 786432)  pack_one(w2 + 131072, W2p1, idx - 655360, 512, 512, 256, 2);
    else if (idx < 790528)  pack_one(rw1,         RW1p, idx - 786432, 24, 32, 128, 1);
    else if (idx < 806912)  pack_one(rw2,         RW2p, idx - 790528, 128, 128, 128, 1);
    else if (idx < 872448)  pack_one(ag1,         AG1p, idx - 806912, 256, 256, 256, 4);
    else if (idx < 905216)  pack_one(ag2,         AG2p, idx - 872448, 256, 256, 128, 4);
}

// ---------------- generic MFMA GEMM: C = epi(A[M,K] @ W + bias) ------------
// W packed ctN=4 (64-col strip per blockIdx.y).
// EPI: 0 fp32, 1 relu->bf16, 2 sigmoid->bf16
template <int EPI>
__global__ __launch_bounds__(256, 4) void gemm_bf16(
        const unsigned short* __restrict__ A, const unsigned short* __restrict__ Bp,
        const float* __restrict__ bias, void* __restrict__ C0,
        int M, int K, int mask, int ldc) {
    extern __shared__ unsigned short As[];
    const int m0 = blockIdx.x * 64, n0 = blockIdx.y * 64;
    const int tid = threadIdx.x;
    const int kc = K >> 3;
    for (int i = tid; i < (kc << 6); i += 256) {
        int r = i / kc, k8 = (i - r * kc) << 3;
        short8 v = {0, 0, 0, 0, 0, 0, 0, 0};
        if (m0 + r < M) v = *(const short8*)(A + (size_t)(m0 + r) * K + k8);
        *(short8*)&As[lds_idx(r, k8, K, mask)] = v;
    }
    __syncthreads();
    const int wid = tid >> 6, lane = tid & 63;
    const int lr = lane & 15, lg = lane >> 4;
    f32x4 acc[4];
#pragma unroll
    for (int ct = 0; ct < 4; ++ct) acc[ct] = f32x4{0.f, 0.f, 0.f, 0.f};
    const unsigned short* Bb = Bp + (size_t)blockIdx.y * ((size_t)K << 6) + (lane << 3);
    const int nk = K >> 5;
    for (int s = 0; s < nk; ++s) {
        int k0 = (s << 5) + (lg << 3);
        short8 af = *(const short8*)&As[lds_idx((wid << 4) + lr, k0, K, mask)];
#pragma unroll
        for (int ct = 0; ct < 4; ++ct) {
            short8 bf = *(const short8*)(Bb + (s << 11) + (ct << 9));
            acc[ct] = mfma16(af, bf, acc[ct]);
        }
    }
#pragma unroll
    for (int ct = 0; ct < 4; ++ct) {
        int c = n0 + (ct << 4) + lr;
        float bb = bias[c];
#pragma unroll
        for (int q = 0; q < 4; ++q) {
            int rg = m0 + (wid << 4) + (lg << 2) + q;
            if (rg >= M) continue;
            float v = acc[ct][q] + bb;
            if (EPI == 0) {
                ((float*)C0)[(size_t)rg * ldc + c] = v;
            } else if (EPI == 1) {
                ((unsigned short*)C0)[(size_t)rg * ldc + c] = f2bf(fmaxf(v, 0.f));
            } else {
                ((unsigned short*)C0)[(size_t)rg * ldc + c] = f2bf(1.f / (1.f + __expf(-v)));
            }
        }
    }
}

// ---------------- fused read MLP: 24->128 relu ->128, + isv gather ---------
__global__ __launch_bounds__(512) void read_mlp_fused(
        const float* __restrict__ reads,
        const unsigned short* __restrict__ RW1p, const unsigned short* __restrict__ RW2p,
        const float* __restrict__ rb1, const float* __restrict__ rb2,
        const uint4* __restrict__ isv4,
        const int* __restrict__ rid_r, const int* __restrict__ rid_a,
        unsigned short* __restrict__ xref, unsigned short* __restrict__ xalt,
        int R, int TR) {
    __shared__ unsigned short Xs[64 * 32];
    __shared__ unsigned short Hs[64 * 128];
    __shared__ int rid_s[64];
    const int m0 = blockIdx.x * 64;
    const int tid = threadIdx.x;
    if (tid < 64) {
        int g = m0 + tid;
        rid_s[tid] = (g < R) ? (g < TR ? rid_r[g] : rid_a[g - TR]) : 0;
    }
    if (tid < 256) {
        int r = tid >> 2, c8 = (tid & 3) << 3;
        short8 v = {0, 0, 0, 0, 0, 0, 0, 0};
        int g = m0 + r;
        if (g < R && c8 < 24) {
            const float* sp = reads + (size_t)g * 24 + c8;
#pragma unroll
            for (int e = 0; e < 8; e++) v[e] = (short)f2bf(sp[e]);
        }
        *(short8*)&Xs[lds_idx(r, c8, 32, 3)] = v;
    }
    __syncthreads();
    const int wid = tid >> 6, lane = tid & 63;
    const int li = lane & 15, lg = lane >> 4;
    f32x4 a1[4];
#pragma unroll
    for (int rt = 0; rt < 4; ++rt) a1[rt] = f32x4{0.f, 0.f, 0.f, 0.f};
    short8 bw1 = *(const short8*)(RW1p + ((size_t)wid << 9) + (lane << 3));
#pragma unroll
    for (int rt = 0; rt < 4; ++rt) {
        short8 af = *(const short8*)&Xs[lds_idx(rt * 16 + li, lg << 3, 32, 3)];
        a1[rt] = mfma16(af, bw1, a1[rt]);
    }
    float b1v = rb1[(wid << 4) + li];
#pragma unroll
    for (int rt = 0; rt < 4; ++rt)
#pragma unroll
        for (int q = 0; q < 4; ++q) {
            int row = rt * 16 + (lg << 2) + q;
            Hs[lds_idx(row, (wid << 4) + li, 128, 15)] = f2bf(fmaxf(a1[rt][q] + b1v, 0.f));
        }
    __syncthreads();
    f32x4 a2[4];
#pragma unroll
    for (int rt = 0; rt < 4; ++rt) a2[rt] = f32x4{0.f, 0.f, 0.f, 0.f};
    const unsigned short* B2 = RW2p + ((size_t)wid << 11) + (lane << 3);
#pragma unroll
    for (int s = 0; s < 4; ++s) {
        short8 bw = *(const short8*)(B2 + (s << 9));
        int k0 = (s << 5) + (lg << 3);
#pragma unroll
        for (int rt = 0; rt < 4; ++rt) {
            short8 ah = *(const short8*)&Hs[lds_idx(rt * 16 + li, k0, 128, 15)];
            a2[rt] = mfma16(ah, bw, a2[rt]);
        }
    }
    float b2v = rb2[(wid << 4) + li];
    unsigned short ov[4][4];
#pragma unroll
    for (int rt = 0; rt < 4; ++rt)
#pragma unroll
        for (int q = 0; q < 4; ++q) ov[rt][q] = f2bf(a2[rt][q] + b2v);
    __syncthreads();                               // all Hs reads done
#pragma unroll
    for (int rt = 0; rt < 4; ++rt)
#pragma unroll
        for (int q = 0; q < 4; ++q) {
            int row = rt * 16 + (lg << 2) + q;
            Hs[row * 128 + (wid << 4) + li] = ov[rt][q];   // OutS linear
        }
    __syncthreads();
    // ---- coalesced store x[:,0:128] + isv gather into x[:,128:256] ----
#pragma unroll
    for (int u = 0; u < 4; ++u) {
        int i = tid + (u << 9);
        int r = i >> 5, j = i & 31;
        int g = m0 + r;
        if (g >= R) continue;
        unsigned short* dst = (g < TR) ? (xref + (size_t)g * 256)
                                       : (xalt + (size_t)(g - TR) * 256);
        if (j < 16)
            *(short8*)(dst + (j << 3)) = *(const short8*)&Hs[r * 128 + (j << 3)];
        else
            ((uint4*)(dst + 128))[j - 16] = isv4[(size_t)rid_s[r] * 16 + (j - 16)];
    }
}

// ---------------- per-variant info MLP + conv + seq linear -> isv bf16 -----
__global__ __launch_bounds__(128) void variant_embed(
        const float* __restrict__ info2d, const float* __restrict__ oh,
        const float* __restrict__ iw1, const float* __restrict__ ib1,
        const float* __restrict__ iw2, const float* __restrict__ ib2,
        const float* __restrict__ cw, const float* __restrict__ cb,
        const float* __restrict__ sw, const float* __restrict__ sb,
        unsigned short* __restrict__ isv, int V) {
    __shared__ float iw1s[10 * 64], iw2s[64 * 64], ib1s[64], ib2s[64];
    __shared__ float cws[32 * 4 * 3], cbs[32];
    __shared__ float ohs[100], cv[736], his[64], infs[10];
    int v = blockIdx.x;
    int t = threadIdx.x;
    for (int i = t; i < 640; i += 128) iw1s[i] = iw1[i];
    for (int i = t; i < 4096; i += 128) iw2s[i] = iw2[i];
    for (int i = t; i < 384; i += 128) cws[i] = cw[i];
    if (t < 64) { ib1s[t] = ib1[t]; ib2s[t] = ib2[t]; }
    if (t < 32) cbs[t] = cb[t];
    for (int i = t; i < 100; i += 128) ohs[i] = oh[(size_t)v * 100 + i];
    if (t < 10) infs[t] = info2d[(size_t)v * 10 + t];
    __syncthreads();
    for (int j = t; j < 736; j += 128) {
        int c = j / 23, p = j - c * 23;
        float a = cbs[c];
#pragma unroll
        for (int i = 0; i < 4; i++)
#pragma unroll
            for (int k = 0; k < 3; k++)
                a += cws[(c * 4 + i) * 3 + k] * ohs[i * 25 + p + k];
        cv[j] = fmaxf(a, 0.f);
    }
    if (t < 64) {
        float h = ib1s[t];
#pragma unroll
        for (int k = 0; k < 10; k++) h += infs[k] * iw1s[k * 64 + t];
        his[t] = fmaxf(h, 0.f);
    }
    __syncthreads();
    if (t < 64) {
        float o = ib2s[t];
        for (int k = 0; k < 64; k++) o += his[k] * iw2s[k * 64 + t];
        isv[(size_t)v * 128 + t] = f2bf(o);
    } else {
        int tt = t - 64;
        float s = sb[tt];
        for (int j = 0; j < 736; j++) s += cv[j] * sw[j * 64 + tt];
        isv[(size_t)v * 128 + 64 + tt] = f2bf(s);
    }
}

// ---------------- segment means (bf16 in/out, vectorized), stacked --------
// m2[0:V] = alt_mean (gates ref rows) ; m2[V:2V] = ref_mean (gates alt rows)
__global__ __launch_bounds__(256) void seg_mean_bf(
        const unsigned short* __restrict__ xref, const int* __restrict__ off_r,
        const unsigned short* __restrict__ xalt, const int* __restrict__ off_a,
        unsigned short* __restrict__ m2, int V) {
    __shared__ float red[2048];
    int b = blockIdx.x;
    int t = threadIdx.x;
    const unsigned short* x;
    const int* off;
    unsigned short* out;
    int v;
    if (b < V) { x = xref; off = off_r; out = m2 + (size_t)(V + b) * 256; v = b; }
    else { x = xalt; off = off_a; out = m2 + (size_t)(b - V) * 256; v = b - V; }
    int s = off[v], e = off[v + 1];
    int g = t >> 5, c8 = (t & 31) << 3;
    float a[8] = {0.f, 0.f, 0.f, 0.f, 0.f, 0.f, 0.f, 0.f};
    for (int r = s + g; r < e; r += 8) {
        short8 vv = *(const short8*)(x + (size_t)r * 256 + c8);
#pragma unroll
        for (int k = 0; k < 8; k++) a[k] += bf2f((unsigned short)vv[k]);
    }
#pragma unroll
    for (int k = 0; k < 8; k++) red[g * 256 + c8 + k] = a[k];
    __syncthreads();
    float acc = red[t];
#pragma unroll
    for (int g2 = 1; g2 < 8; g2++) acc += red[g2 * 256 + t];
    out[t] = f2bf(acc / (float)(e - s));
}

// ---------------- fused gated residual block (64-row tile, 8 waves) --------
// stage Xs -> GEMM1 (swapped, packed W1) -> epi1 (bf16 gate) -> Hs
//   -> GEMM2 (swapped, packed W2) -> direct residual RMW store (no OutF).
__global__ __launch_bounds__(512, 4) void fused_block(
        unsigned short* __restrict__ xref, unsigned short* __restrict__ xalt,
        const unsigned short* __restrict__ W1p,   // packed [8][8][4][64][8]
        const unsigned short* __restrict__ W2p,   // packed [8][16][2][64][8]
        const float* __restrict__ b1, const float* __restrict__ b2,
        const unsigned short* __restrict__ gate_r, const unsigned short* __restrict__ gate_a,
        const int* __restrict__ rid_r, const int* __restrict__ rid_a,
        int TR, int TA, int ntr) {
    __shared__ unsigned short U[64 * 512];        // 64 KB union (Xs 32 / Hs 64)
    __shared__ int rid_s[64];
    // bijective XCD swizzle (m204)
    const int nwg = gridDim.x;
    const int bid0 = blockIdx.x;
    const int q8 = nwg >> 3, r8 = nwg & 7;
    const int xcd = bid0 & 7;
    const int bid = (xcd < r8 ? xcd * (q8 + 1) : r8 * (q8 + 1) + (xcd - r8) * q8)
                    + (bid0 >> 3);
    const bool isref = bid < ntr;
    const int m0 = (isref ? bid : bid - ntr) * 64;
    const int M = isref ? TR : TA;
    unsigned short* x = isref ? xref : xalt;
    const unsigned short* gate = isref ? gate_r : gate_a;
    const int* rid = isref ? rid_r : rid_a;
    const int tid = threadIdx.x;
    if (tid < 64) rid_s[tid] = (m0 + tid < M) ? rid[m0 + tid] : 0;
    // ---- stage X (pre-swizzled source, linear LDS dest) ----
#pragma unroll
    for (int u = 0; u < 4; ++u) {
        int i = tid + (u << 9);
        int r = i >> 5, j = i & 31;
        short8 v = {0, 0, 0, 0, 0, 0, 0, 0};
        if (m0 + r < M)
            v = *(const short8*)(x + (size_t)(m0 + r) * 256 + ((j ^ (r & 15)) << 3));
        *(short8*)&U[r * 256 + (j << 3)] = v;
    }
    __syncthreads();
    const int wid = tid >> 6, lane = tid & 63;
    const int li = lane & 15, lg = lane >> 4;
    // ---- GEMM1 (swapped): wave owns 64-col strip; packed W1 ----
    const int ns = wid << 6;
    f32x4 acc1[4][4];
#pragma unroll
    for (int i = 0; i < 4; ++i)
#pragma unroll
        for (int j = 0; j < 4; ++j) acc1[i][j] = f32x4{0.f, 0.f, 0.f, 0.f};
    const unsigned short* W1b = W1p + ((size_t)wid << 14) + (lane << 3);
#pragma unroll
    for (int s = 0; s < 8; ++s) {
        short8 awc[4];
#pragma unroll
        for (int ct = 0; ct < 4; ++ct)
            awc[ct] = *(const short8*)(W1b + (s << 11) + (ct << 9));
        int k0 = (s << 5) + (lg << 3);
        __builtin_amdgcn_s_setprio(1);
#pragma unroll
        for (int rt = 0; rt < 4; ++rt) {
            short8 bx = *(const short8*)&U[lds_idx(rt * 16 + li, k0, 256, 15)];
#pragma unroll
            for (int ct = 0; ct < 4; ++ct)
                acc1[rt][ct] = mfma16(awc[ct], bx, acc1[rt][ct]);
        }
        __builtin_amdgcn_s_setprio(0);
    }
    __syncthreads();                              // Xs dead; U becomes Hs
    // ---- epilogue 1: relu * gate(bf16) -> Hs (packed 8B writes) ----
    // acc1[rt][ct][q]: H[m=rt*16+li][n=ns+ct*16+lg*4+q]
#pragma unroll
    for (int rt = 0; rt < 4; ++rt) {
        int m = rt * 16 + li;
        const unsigned short* grow = gate + (size_t)rid_s[m] * 512 + ns + (lg << 2);
        const float* b1p = b1 + ns + (lg << 2);
#pragma unroll
        for (int ct = 0; ct < 4; ++ct) {
            uint2 gw = *(const uint2*)(grow + (ct << 4));
            float4 bv = *(const float4*)(b1p + (ct << 4));
            float g0 = bf2f((unsigned short)(gw.x & 0xffff));
            float g1 = bf2f((unsigned short)(gw.x >> 16));
            float g2 = bf2f((unsigned short)(gw.y & 0xffff));
            float g3 = bf2f((unsigned short)(gw.y >> 16));
            unsigned h0 = f2bf(fmaxf(acc1[rt][ct][0] + bv.x, 0.f) * g0);
            unsigned h1 = f2bf(fmaxf(acc1[rt][ct][1] + bv.y, 0.f) * g1);
            unsigned h2 = f2bf(fmaxf(acc1[rt][ct][2] + bv.z, 0.f) * g2);
            unsigned h3 = f2bf(fmaxf(acc1[rt][ct][3] + bv.w, 0.f) * g3);
            uint2 pk;
            pk.x = h0 | (h1 << 16);
            pk.y = h2 | (h3 << 16);
            int n = ns + (ct << 4) + (lg << 2);
            *(uint2*)&U[lds_idx(m, n, 512, 15)] = pk;
        }
    }
    __syncthreads();
    // ---- GEMM2 (swapped): wave owns 32-col strip cs; mfma(W2frag, Hfrag)
    //      -> acc2[rt][ct][q] = O[m=rt*16+li][c=cs+ct*16+lg*4+q] ----
    const int cs = wid << 5;
    f32x4 acc2[4][2];
#pragma unroll
    for (int i = 0; i < 4; ++i)
#pragma unroll
        for (int j = 0; j < 2; ++j) acc2[i][j] = f32x4{0.f, 0.f, 0.f, 0.f};
    const unsigned short* W2b = W2p + ((size_t)wid << 14) + (lane << 3);
    short8 bwc[2], bwn[2];
#pragma unroll
    for (int ct = 0; ct < 2; ++ct) bwc[ct] = *(const short8*)(W2b + (ct << 9));
#pragma unroll
    for (int s = 0; s < 16; ++s) {
        if (s < 15) {
#pragma unroll
            for (int ct = 0; ct < 2; ++ct)
                bwn[ct] = *(const short8*)(W2b + ((s + 1) << 10) + (ct << 9));
        }
        int k0 = (s << 5) + (lg << 3);
        __builtin_amdgcn_s_setprio(1);
#pragma unroll
        for (int rt = 0; rt < 4; ++rt) {
            short8 ah = *(const short8*)&U[lds_idx(rt * 16 + li, k0, 512, 15)];
#pragma unroll
            for (int ct = 0; ct < 2; ++ct)
                acc2[rt][ct] = mfma16(bwc[ct], ah, acc2[rt][ct]);
        }
        __builtin_amdgcn_s_setprio(0);
#pragma unroll
        for (int ct = 0; ct < 2; ++ct) bwc[ct] = bwn[ct];
    }
    // ---- direct residual RMW store (8B per lane, 16 rows x 32B/instr) ----
#pragma unroll
    for (int rt = 0; rt < 4; ++rt) {
        int m = rt * 16 + li;
        if (m0 + m >= M) continue;
        unsigned short* xrow = x + (size_t)(m0 + m) * 256;
#pragma unroll
        for (int ct = 0; ct < 2; ++ct) {
            int c = cs + (ct << 4) + (lg << 2);
            uint2 xv = *(const uint2*)(xrow + c);
            float4 bb = *(const float4*)(b2 + c);
            unsigned o0 = f2bf(bf2f((unsigned short)(xv.x & 0xffff)) + acc2[rt][ct][0] + bb.x);
            unsigned o1 = f2bf(bf2f((unsigned short)(xv.x >> 16)) + acc2[rt][ct][1] + bb.y);
            unsigned o2 = f2bf(bf2f((unsigned short)(xv.y & 0xffff)) + acc2[rt][ct][2] + bb.z);
            unsigned o3 = f2bf(bf2f((unsigned short)(xv.y >> 16)) + acc2[rt][ct][3] + bb.w);
            uint2 pk;
            pk.x = o0 | (o1 << 16);
            pk.y = o2 | (o3 << 16);
            *(uint2*)(xrow + c) = pk;
        }
    }
}

// ---------------- weighted alt mean (wsum computed in-kernel) ---------------
__global__ __launch_bounds__(256) void alt_weighted_mean_bf(
        const unsigned short* __restrict__ xalt, const float* __restrict__ au,
        const int* __restrict__ off_a, unsigned short* __restrict__ av, int V) {
    __shared__ float red[2048];
    __shared__ float wred[256];
    int v = blockIdx.x;
    int t = threadIdx.x;
    int s = off_a[v], e = off_a[v + 1];
    float wp = 0.f;
    for (int r = s + t; r < e; r += 256) wp += 1.2f - 0.4f * au[r];
    wred[t] = wp;
    __syncthreads();
    for (int d = 128; d; d >>= 1) {
        if (t < d) wred[t] += wred[t + d];
        __syncthreads();
    }
    float inv = 1.f / wred[0];
    int g = t >> 5, c8 = (t & 31) << 3;
    float a[8] = {0.f, 0.f, 0.f, 0.f, 0.f, 0.f, 0.f, 0.f};
    for (int r = s + g; r < e; r += 8) {
        float w = (1.2f - 0.4f * au[r]) * inv;
        short8 vv = *(const short8*)(xalt + (size_t)r * 256 + c8);
#pragma unroll
        for (int k = 0; k < 8; k++) a[k] += bf2f((unsigned short)vv[k]) * w;
    }
#pragma unroll
    for (int k = 0; k < 8; k++) red[g * 256 + c8 + k] = a[k];
    __syncthreads();
    float acc = red[t];
#pragma unroll
    for (int g2 = 1; g2 < 8; g2++) acc += red[g2 * 256 + t];
    av[(size_t)v * 256 + t] = f2bf(acc);
}

// ---------------------------------------------------------------------------
extern "C" void kernel_launch(void* const* d_in, const int* in_sizes, int n_in,
                              void* d_out, int out_size, void* d_ws, size_t ws_size,
                              hipStream_t stream) {
    const float* reads = (const float*)d_in[0];
    const float* info2d = (const float*)d_in[1];
    const float* oh = (const float*)d_in[2];
    const float* au = (const float*)d_in[3];
    const int* ref_counts = (const int*)d_in[4];
    const int* alt_counts = (const int*)d_in[5];
    const float* rw1 = (const float*)d_in[6];
    const float* rb1 = (const float*)d_in[7];
    const float* rw2 = (const float*)d_in[8];
    const float* rb2 = (const float*)d_in[9];
    const float* iw1 = (const float*)d_in[10];
    const float* ib1 = (const float*)d_in[11];
    const float* iw2 = (const float*)d_in[12];
    const float* ib2 = (const float*)d_in[13];
    const float* cw = (const float*)d_in[14];
    const float* cb = (const float*)d_in[15];
    const float* sw = (const float*)d_in[16];
    const float* sb = (const float*)d_in[17];
    const float* blk_w1 = (const float*)d_in[18];
    const float* blk_b1 = (const float*)d_in[19];
    const float* blk_wg = (const float*)d_in[20];
    const float* blk_bg = (const float*)d_in[21];
    const float* blk_w2 = (const float*)d_in[22];
    const float* blk_b2 = (const float*)d_in[23];
    const float* agg_w1 = (const float*)d_in[24];
    const float* agg_b1 = (const float*)d_in[25];
    const float* agg_w2 = (const float*)d_in[26];
    const float* agg_b2 = (const float*)d_in[27];

    const int R = in_sizes[0] / 24;
    const int TA = in_sizes[3];
    const int TR = R - TA;
    const int V = in_sizes[4];

    size_t p = 0;
    auto carve = [&](size_t bytes) -> void* {
        void* q = (char*)d_ws + p;
        p = (p + bytes + 255) & ~(size_t)255;
        return q;
    };
    int* off_r = (int*)carve((V + 1) * sizeof(int));
    int* off_a = (int*)carve((V + 1) * sizeof(int));
    int* rid_r = (int*)carve((size_t)TR * sizeof(int));
    int* rid_a = (int*)carve((size_t)TA * sizeof(int));
    unsigned short* isv = (unsigned short*)carve((size_t)V * 128 * 2);
    unsigned short* xref = (unsigned short*)carve((size_t)TR * 256 * 2);
    unsigned short* xalt = (unsigned short*)carve((size_t)TA * 256 * 2);
    unsigned short* W1p0 = (unsigned short*)carve((size_t)512 * 256 * 2);
    unsigned short* W1p1 = (unsigned short*)carve((size_t)512 * 256 * 2);
    unsigned short* Wgp0 = (unsigned short*)carve((size_t)512 * 256 * 2);
    unsigned short* Wgp1 = (unsigned short*)carve((size_t)512 * 256 * 2);
    unsigned short* W2p0 = (unsigned short*)carve((size_t)256 * 512 * 2);
    unsigned short* W2p1 = (unsigned short*)carve((size_t)256 * 512 * 2);
    unsigned short* RW1p = (unsigned short*)carve((size_t)128 * 32 * 2);
    unsigned short* RW2p = (unsigned short*)carve((size_t)128 * 128 * 2);
    unsigned short* AG1p = (unsigned short*)carve((size_t)256 * 256 * 2);
    unsigned short* AG2p = (unsigned short*)carve((size_t)128 * 256 * 2);
    unsigned short* m2 = (unsigned short*)carve((size_t)2 * V * 256 * 2);    // [alt;ref] means
    unsigned short* gate2 = (unsigned short*)carve((size_t)2 * V * 512 * 2); // bf16 gates
    unsigned short* avb_bf = (unsigned short*)carve((size_t)V * 256 * 2);
    unsigned short* aggh_bf = (unsigned short*)carve((size_t)V * 256 * 2);
    (void)ws_size; (void)n_in; (void)out_size;

    // ---- offsets/ids + weight packing + variant embeddings ----
    scan_fill<<<2, 256, 0, stream>>>(ref_counts, alt_counts, off_r, off_a, rid_r, rid_a, V);
    pack_all<<<3536, 256, 0, stream>>>(blk_w1, blk_wg, blk_w2, rw1, rw2, agg_w1, agg_w2,
                                       W1p0, W1p1, Wgp0, Wgp1, W2p0, W2p1,
                                       RW1p, RW2p, AG1p, AG2p);
    variant_embed<<<V, 128, 0, stream>>>(info2d, oh, iw1, ib1, iw2, ib2, cw, cb, sw, sb, isv, V);

    // ---- fused read MLP + isv gather -> full x rows ----
    read_mlp_fused<<<(R + 63) / 64, 512, 0, stream>>>(
        reads, RW1p, RW2p, rb1, rb2, (const uint4*)isv, rid_r, rid_a, xref, xalt, R, TR);

    // ---- 2 gated residual blocks ----
    const int ntr = (TR + 63) / 64, nta = (TA + 63) / 64;
    for (int it = 0; it < 2; ++it) {
        const unsigned short* W1p = it ? W1p1 : W1p0;
        const unsigned short* Wgp = it ? Wgp1 : Wgp0;
        const unsigned short* W2p = it ? W2p1 : W2p0;
        const float* B1 = blk_b1 + (size_t)it * 512;
        const float* Bg = blk_bg + (size_t)it * 512;
        const float* B2 = blk_b2 + (size_t)it * 256;

        seg_mean_bf<<<2 * V, 256, 0, stream>>>(xref, off_r, xalt, off_a, m2, V);
        dim3 gg(2 * V / 64, 8);
        gemm_bf16<2><<<gg, 256, 64 * 256 * 2, stream>>>(m2, Wgp, Bg, gate2,
                                                        2 * V, 256, 15, 512);
        fused_block<<<ntr + nta, 512, 0, stream>>>(xref, xalt, W1p, W2p, B1, B2,
                                                   gate2, gate2 + (size_t)V * 512,
                                                   rid_r, rid_a, TR, TA, ntr);
    }

    // ---- weighted alt means + agg MLP ----
    alt_weighted_mean_bf<<<V, 256, 0, stream>>>(xalt, au, off_a, avb_bf, V);
    {
        dim3 ga(V / 64, 4);
        gemm_bf16<1><<<ga, 256, 64 * 256 * 2, stream>>>(avb_bf, AG1p, agg_b1, aggh_bf,
                                                        V, 256, 15, 256);
        dim3 go(V / 64, 2);
        gemm_bf16<0><<<go, 256, 64 * 256 * 2, stream>>>(aggh_bf, AG2p, agg_b2, d_out,
                                                        V, 256, 15, 128);
    }
}